// Round 8
// baseline (43.561 us; speedup 1.0000x reference)
//
#include <hip/hip_runtime.h>

// Acrobot GN step, fused bf16-MFMA. rows = 2*B, 32 rows per 2-wave WG tile.
//   G1: e1  = relu(A1 @ in32)            A1=[We1[10:17];be1]^T, K=32; B built in regs
//   G2: e2  = relu(A2 @ e1 + be2)        A2=We2^T, K=128; be2 via MFMA C-init
//   G3: hdd = relu(A3 @ [e2[row^1]; sender,1]) K=160; bn1 folded in A3ext col2
//   G4: delta = A4 @ hdd + bn2           A4=Wn2^T pad [16][128]; bn2 via C-init; direct store
//
// R7 post-mortem: spill gone (WRITE 2MB), HBM 1%, but 3 barriers/tile serialize stage
// latencies (MfmaUtil 20 / VALU 28 / ~50% stall at 2 waves/SIMD).
// R8: software-pipeline across tiles, 2 barriers/tile:
//   P1: G1(t+1) || G3(t)      (independent MFMA chains fill each other's latency)
//   P2: G4(t) || G2(t+1); build B(t+2); prefetch x(t+3)
// Single-buffered LDS is safe: each buffer's writer/reader are 1 barrier apart.

typedef __attribute__((ext_vector_type(8))) short bf16x8;
typedef __attribute__((ext_vector_type(4))) float f32x4;

union U4B { uint4 u; bf16x8 b; };

__device__ __forceinline__ unsigned short f2bf(float f) {
  union { float f; unsigned u; } v; v.f = f;
  return (unsigned short)((v.u + 0x7FFFu + ((v.u >> 16) & 1u)) >> 16);  // RNE
}

__device__ __forceinline__ unsigned cvtpk(float lo, float hi) {
  unsigned r;
  asm("v_cvt_pk_bf16_f32 %0, %1, %2" : "=v"(r) : "v"(lo), "v"(hi));
  return r;
}

// ---------------- weight prep: bf16 A-operand images in ws ----------------
// shorts: A1c [128j][8k] @0 ; A3e [128j][8k] @1024 ; A4c [2jp][128k] @2048 (2304 total);
//         A2 [128j][128k] @4096 ; A3 main [128j][128k] @20480. 36864 shorts = 73728 B.
__global__ void gn_prep(const float* __restrict__ We1, const float* __restrict__ be1,
                        const float* __restrict__ We2, const float* __restrict__ Wn1,
                        const float* __restrict__ bn1, const float* __restrict__ Wn2,
                        unsigned short* __restrict__ wsA) {
  int t = blockIdx.x * 256 + threadIdx.x;
  if (t < 1024) {                       // A1 compact: k<7 -> We1 rows 10..16 ; k==7 -> be1
    int j = t >> 3, k = t & 7;
    wsA[t] = f2bf((k < 7) ? We1[(10 + k) * 128 + j] : be1[j]);
  } else if (t < 2048) {                // A3ext compact: c0=Wn1r10, c1=Wn1r11, c2=bn1
    int t2 = t - 1024; int j = t2 >> 3, c = t2 & 7;
    float v = (c == 0) ? Wn1[10 * 128 + j] : (c == 1) ? Wn1[11 * 128 + j]
            : (c == 2) ? bn1[j] : 0.0f;
    wsA[t] = f2bf(v);
  } else if (t < 2304) {                // A4 compact: 2 rows of Wn2^T
    int t2 = t - 2048; int jp = t2 >> 7, k = t2 & 127;
    wsA[t] = f2bf(Wn2[k * 2 + jp]);
  } else if (t >= 4096 && t < 20480) {  // A2 = We2^T
    int t2 = t - 4096; int j = t2 >> 7, k = t2 & 127;
    wsA[t] = f2bf(We2[k * 128 + j]);
  } else if (t >= 20480 && t < 36864) { // A3 main = Wn1[12:140]^T
    int t2 = t - 20480; int j = t2 >> 7, k = t2 & 127;
    wsA[t] = f2bf(Wn1[(12 + k) * 128 + j]);
  }
}

// ---------------- main fused kernel ----------------
#define NTILES  8192    // 262144 rows / 32 rows per tile
#define GSTRIDE 1024    // grid size

__global__ __launch_bounds__(128) __attribute__((amdgpu_waves_per_eu(2, 2)))
void gn_main(
    const float* __restrict__ x, const float* __restrict__ u,
    const float* __restrict__ nmean, const float* __restrict__ nstd,
    const float* __restrict__ emean, const float* __restrict__ estd,
    const float* __restrict__ be2, const float* __restrict__ bn2,
    const unsigned short* __restrict__ wsA,
    float* __restrict__ out)
{
  __shared__ __align__(16) unsigned short bufE1[32 * 128];  // 8KB
  __shared__ __align__(16) unsigned short bufE2[32 * 128];  // 8KB
  __shared__ __align__(16) unsigned short bufHD[32 * 128];  // 8KB
  __shared__ __align__(16) unsigned short aLDS[2304];       // A1c|A3e|A4c, 4.5KB

  const int tid  = threadIdx.x;
  const int lane = tid & 63;
  const int Mg   = tid >> 6;     // wave = feature half 0/1
  const int c15  = lane & 15;
  const int g    = lane >> 4;    // 0..3

  // ---- copy compact A-images into LDS (one time) ----
  for (int t = tid; t < 1152; t += 128)
    ((unsigned*)aLDS)[t] = ((const unsigned*)wsA)[t];

  // ---- resident A-operand fragments: A2, A3-main only (128 regs = AGPR capacity) ----
  bf16x8 A2f[4][4], A3f[4][4];
  const int jbw = Mg * 64;
  #pragma unroll
  for (int m = 0; m < 4; ++m) {
    int j = jbw + m * 16 + c15;
    #pragma unroll
    for (int kk = 0; kk < 4; ++kk) {
      A2f[m][kk] = *(const bf16x8*)(wsA + 4096  + j * 128 + kk * 32 + g * 8);
      A3f[m][kk] = *(const bf16x8*)(wsA + 20480 + j * 128 + kk * 32 + g * 8);
    }
  }

  const float nm0 = nmean[0], nm1 = nmean[1];
  const float is0 = 1.0f / nstd[0], is1 = 1.0f / nstd[1];
  const float em0 = emean[0], ie0 = 1.0f / estd[0];
  const float cea1 = (0.0f - emean[1]) / estd[1];
  const float cea2 = (0.0f - emean[2]) / estd[2];
  const float bn20 = bn2[0], bn21 = bn2[1];
  const unsigned cpkw = cvtpk(cea2, 1.0f);   // B dword3: [cea2, 1.0]

  // ---------------- stage lambdas ----------------
  auto loadXU = [&](int t, float4* xv, float* uv) {
    if (g == 0) {
      #pragma unroll
      for (int n = 0; n < 2; ++n) {
        int b = t * 16 + n * 8 + (c15 >> 1);
        xv[n] = *(const float4*)(x + b * 4);
        uv[n] = u[b];
      }
    }
  };

  auto buildB = [&](const float4* xv, const float* uv, bf16x8* Bv, unsigned* pks) {
    #pragma unroll
    for (int n = 0; n < 2; ++n) {
      uint4 bu = (uint4){0u, 0u, 0u, 0u};
      if (g == 0) {                     // only k=0..7 nonzero; g==0 lanes hold them
        float a0 = (xv[n].x - nm0) * is0;   // node0 theta
        float a1 = (xv[n].z - nm1) * is1;   // node0 v
        float b0 = (xv[n].y - nm0) * is0;   // node1 theta
        float b1 = (xv[n].w - nm1) * is1;   // node1 v
        bool  e  = (c15 & 1);               // row parity = edge index
        float s0 = e ? b0 : a0, s1 = e ? b1 : a1;   // sender  feats
        float r0 = e ? a0 : b0, r1 = e ? a1 : b1;   // receiver feats
        float ea0 = (uv[n] - em0) * ie0;
        bu.x = cvtpk(s0, s1);
        bu.y = cvtpk(r0, r1);
        bu.z = cvtpk(ea0, cea1);
        bu.w = cpkw;
      }
      pks[n] = bu.x;                    // sender feats, reused as G3 node feats
      U4B t; t.u = bu; Bv[n] = t.b;
    }
  };

  auto runG1 = [&](const bf16x8* Bv) {
    bf16x8 A1t[4];
    #pragma unroll
    for (int m = 0; m < 4; ++m) {
      uint4 av = (uint4){0u, 0u, 0u, 0u};
      if (g == 0) av = *(const uint4*)((const char*)aLDS + (jbw + m * 16 + c15) * 16);
      U4B ta; ta.u = av; A1t[m] = ta.b;
    }
    f32x4 acc[4][2];
    #pragma unroll
    for (int m = 0; m < 4; ++m)
      #pragma unroll
      for (int n = 0; n < 2; ++n) acc[m][n] = (f32x4){0.f, 0.f, 0.f, 0.f};
    #pragma unroll
    for (int n = 0; n < 2; ++n)
      #pragma unroll
      for (int m = 0; m < 4; ++m)
        acc[m][n] = __builtin_amdgcn_mfma_f32_16x16x32_bf16(A1t[m], Bv[n], acc[m][n], 0, 0, 0);
    #pragma unroll
    for (int m = 0; m < 4; ++m) {
      int jb2 = (jbw + m * 16 + g * 4) * 2;
      #pragma unroll
      for (int n = 0; n < 2; ++n) {
        int row = n * 16 + c15;
        f32x4 v = acc[m][n];
        uint2 pk;
        pk.x = cvtpk(fmaxf(v[0], 0.f), fmaxf(v[1], 0.f));
        pk.y = cvtpk(fmaxf(v[2], 0.f), fmaxf(v[3], 0.f));
        *(uint2*)((char*)bufE1 + row * 256 + (jb2 ^ ((row & 7) << 4))) = pk;
      }
    }
  };

  auto runG2 = [&]() {
    f32x4 acc[4][2];
    #pragma unroll
    for (int m = 0; m < 4; ++m) {
      f32x4 bz = *(const f32x4*)(be2 + jbw + m * 16 + g * 4);
      acc[m][0] = bz; acc[m][1] = bz;
    }
    #pragma unroll
    for (int n = 0; n < 2; ++n) {
      int row = n * 16 + c15;
      int rb = row * 256, sw = (row & 7) << 4;
      #pragma unroll
      for (int kk = 0; kk < 4; ++kk) {
        bf16x8 B = *(const bf16x8*)((const char*)bufE1 + rb + ((kk * 64 + g * 16) ^ sw));
        #pragma unroll
        for (int m = 0; m < 4; ++m)
          acc[m][n] = __builtin_amdgcn_mfma_f32_16x16x32_bf16(A2f[m][kk], B, acc[m][n], 0, 0, 0);
      }
    }
    #pragma unroll
    for (int m = 0; m < 4; ++m) {
      int jb2 = (jbw + m * 16 + g * 4) * 2;
      #pragma unroll
      for (int n = 0; n < 2; ++n) {
        int row = n * 16 + c15;
        f32x4 v = acc[m][n];
        uint2 pk;
        pk.x = cvtpk(fmaxf(v[0], 0.f), fmaxf(v[1], 0.f));
        pk.y = cvtpk(fmaxf(v[2], 0.f), fmaxf(v[3], 0.f));
        *(uint2*)((char*)bufE2 + row * 256 + (jb2 ^ ((row & 7) << 4))) = pk;
      }
    }
  };

  auto runG3 = [&](const unsigned* pks) {
    bf16x8 A3et[4];
    #pragma unroll
    for (int m = 0; m < 4; ++m) {   // transient ext fragments from LDS
      uint4 av = (uint4){0u, 0u, 0u, 0u};
      if (g == 0) av = *(const uint4*)((const char*)aLDS + 2048 + (jbw + m * 16 + c15) * 16);
      U4B ta; ta.u = av; A3et[m] = ta.b;
    }
    f32x4 acc[4][2];
    #pragma unroll
    for (int m = 0; m < 4; ++m)
      #pragma unroll
      for (int n = 0; n < 2; ++n) acc[m][n] = (f32x4){0.f, 0.f, 0.f, 0.f};
    #pragma unroll
    for (int n = 0; n < 2; ++n) {
      int rr0 = n * 16 + c15;
      int rsw = rr0 ^ 1;                       // aggregation = paired-row swap
      int rb = rsw * 256, sw = (rsw & 7) << 4;
      #pragma unroll
      for (int kk = 0; kk < 4; ++kk) {
        bf16x8 B = *(const bf16x8*)((const char*)bufE2 + rb + ((kk * 64 + g * 16) ^ sw));
        #pragma unroll
        for (int m = 0; m < 4; ++m)
          acc[m][n] = __builtin_amdgcn_mfma_f32_16x16x32_bf16(A3f[m][kk], B, acc[m][n], 0, 0, 0);
      }
      // K-chunk 4: node feats (= sender feats saved from G1 build) + const-1 (bn1 col)
      uint4 b4u = (uint4){0u, 0u, 0u, 0u};
      if (g == 0) { b4u.x = pks[n]; b4u.y = 0x00003F80u; }
      U4B t4; t4.u = b4u;
      #pragma unroll
      for (int m = 0; m < 4; ++m)
        acc[m][n] = __builtin_amdgcn_mfma_f32_16x16x32_bf16(A3et[m], t4.b, acc[m][n], 0, 0, 0);
    }
    #pragma unroll
    for (int m = 0; m < 4; ++m) {
      int jb2 = (jbw + m * 16 + g * 4) * 2;
      #pragma unroll
      for (int n = 0; n < 2; ++n) {
        int row = n * 16 + c15;
        f32x4 v = acc[m][n];
        uint2 pk;
        pk.x = cvtpk(fmaxf(v[0], 0.f), fmaxf(v[1], 0.f));
        pk.y = cvtpk(fmaxf(v[2], 0.f), fmaxf(v[3], 0.f));
        *(uint2*)((char*)bufHD + row * 256 + (jb2 ^ ((row & 7) << 4))) = pk;
      }
    }
  };

  auto runG4 = [&](int rowbase) {
    int rr = Mg * 16 + c15;
    int rb = rr * 256, sw = (rr & 7) << 4;
    f32x4 a4 = (f32x4){bn20, bn21, 0.f, 0.f};
    #pragma unroll
    for (int kk = 0; kk < 4; ++kk) {
      uint4 av = (uint4){0u, 0u, 0u, 0u};   // transient A4 fragment from LDS
      if (c15 < 2) av = *(const uint4*)((const char*)aLDS + 4096 + c15 * 256 + kk * 64 + g * 16);
      U4B ta; ta.u = av;
      bf16x8 B = *(const bf16x8*)((const char*)bufHD + rb + ((kk * 64 + g * 16) ^ sw));
      a4 = __builtin_amdgcn_mfma_f32_16x16x32_bf16(ta.b, B, a4, 0, 0, 0);
    }
    if (g == 0) {                // lane holds delta c0,c1 for row rr
      int gr = rowbase + rr;
      int bidx = gr >> 1, k = gr & 1;
      out[bidx * 4 + k]     = x[bidx * 4 + k]     + a4[0];
      out[bidx * 4 + k + 2] = x[bidx * 4 + k + 2] + a4[1];
    }
  };

  // ---------------- pipelined schedule: 2 barriers per tile ----------------
  const int t0 = blockIdx.x;
  float4 xva[2], xvb[2], xvN[2];
  float  uva[2], uvb[2], uvN[2];
  bf16x8 Bv[2];
  unsigned pks_cur[2], pks_next[2];

  loadXU(t0, xva, uva);                                // tile t0
  if (t0 + GSTRIDE < NTILES)     loadXU(t0 + GSTRIDE, xvb, uvb);       // t0+s
  __syncthreads();                                     // aLDS ready

  buildB(xva, uva, Bv, pks_cur);
  runG1(Bv);                                           // G1(t0)
  __syncthreads();

  runG2();                                             // G2(t0)
  buildB(xvb, uvb, Bv, pks_next);                      // Bv <- t0+s
  if (t0 + 2 * GSTRIDE < NTILES) loadXU(t0 + 2 * GSTRIDE, xvN, uvN);   // t0+2s
  __syncthreads();

  for (int tile = t0; tile < NTILES; tile += GSTRIDE) {
    const bool hasNext = (tile + GSTRIDE) < NTILES;
    // ---- P1: G1(t+1) || G3(t) ----
    if (hasNext) runG1(Bv);
    runG3(pks_cur);
    __syncthreads();
    // ---- P2: G4(t) || G2(t+1); build B(t+2); prefetch x(t+3) ----
    runG4(tile * 32);
    if (hasNext) runG2();
    pks_cur[0] = pks_next[0]; pks_cur[1] = pks_next[1];
    buildB(xvN, uvN, Bv, pks_next);                    // data for t+2s (unused if invalid)
    if (tile + 3 * GSTRIDE < NTILES) loadXU(tile + 3 * GSTRIDE, xvN, uvN);
    __syncthreads();
  }
}

extern "C" void kernel_launch(void* const* d_in, const int* in_sizes, int n_in,
                              void* d_out, int out_size, void* d_ws, size_t ws_size,
                              hipStream_t stream) {
  const float* x   = (const float*)d_in[0];
  const float* u   = (const float*)d_in[1];
  const float* nm  = (const float*)d_in[2];
  const float* ns  = (const float*)d_in[3];
  const float* em  = (const float*)d_in[4];
  const float* es  = (const float*)d_in[5];
  const float* We1 = (const float*)d_in[6];
  const float* be1 = (const float*)d_in[7];
  const float* We2 = (const float*)d_in[8];
  const float* be2 = (const float*)d_in[9];
  const float* Wn1 = (const float*)d_in[10];
  const float* bn1 = (const float*)d_in[11];
  const float* Wn2 = (const float*)d_in[12];
  const float* bn2 = (const float*)d_in[13];
  unsigned short* wsA = (unsigned short*)d_ws;   // needs 73728 bytes
  float* out = (float*)d_out;

  gn_prep<<<144, 256, 0, stream>>>(We1, be1, We2, Wn1, bn1, Wn2, wsA);
  gn_main<<<GSTRIDE, 128, 0, stream>>>(x, u, nm, ns, em, es, be2, bn2, wsA, out);
}